// Round 6
// baseline (2355.237 us; speedup 1.0000x reference)
//
#include <hip/hip_runtime.h>
#include <hip/hip_bf16.h>

#define BB 8
#define TT 1024
#define DM 512
#define NH 8
#define DK 64
#define DH 2048
#define NL 8
#define ND 8192

typedef __attribute__((ext_vector_type(8))) short short8v;
typedef __attribute__((ext_vector_type(8))) _Float16 f16x8;
typedef __attribute__((ext_vector_type(4))) float f32x4;
typedef __attribute__((ext_vector_type(4))) unsigned short ushort4v;
typedef unsigned short u16;

#define MFMA16(a, b, c) __builtin_amdgcn_mfma_f32_16x16x32_bf16(a, b, c, 0, 0, 0)
#define MFMAH(a, b, c)  __builtin_amdgcn_mfma_f32_16x16x32_f16(a, b, c, 0, 0, 0)

__device__ __forceinline__ u16 bf16_bits(float f) {
  union { __hip_bfloat16 h; u16 u; } cv;
  cv.h = __float2bfloat16(f);
  return cv.u;
}
__device__ __forceinline__ float bits_to_f32(u16 u) {
  union { __hip_bfloat16 h; u16 u; } cv;
  cv.u = u;
  return __bfloat162float(cv.h);
}

__device__ __forceinline__ void gload16(const void* g, void* l) {
  __builtin_amdgcn_global_load_lds(
      (const __attribute__((address_space(1))) unsigned int*)g,
      (__attribute__((address_space(3))) unsigned int*)l, 16, 0, 0);
}

#define WAITVM(N) asm volatile("s_waitcnt vmcnt(" #N ")" ::: "memory")
#define BAR() { __builtin_amdgcn_s_barrier(); asm volatile("" ::: "memory"); }

// ---------------- block reduce (256 threads, 2 accumulators) ----------------
__device__ __forceinline__ void block_reduce2(float& a, float& b) {
  #pragma unroll
  for (int off = 32; off > 0; off >>= 1) {
    a += __shfl_down(a, off, 64);
    b += __shfl_down(b, off, 64);
  }
  __shared__ float sa[4], sb[4];
  int w = threadIdx.x >> 6;
  if ((threadIdx.x & 63) == 0) { sa[w] = a; sb[w] = b; }
  __syncthreads();
  if (threadIdx.x == 0) {
    sa[0] = sa[0] + sa[1] + sa[2] + sa[3];
    sb[0] = sb[0] + sb[1] + sb[2] + sb[3];
  }
  __syncthreads();
  a = sa[0]; b = sb[0];
}

// ---------------- embedding + LN ----------------
__global__ __launch_bounds__(256) void embed_ln_kernel(
    const int* __restrict__ x, const float* __restrict__ emb,
    const float* __restrict__ pos, float* __restrict__ h,
    u16* __restrict__ hh, _Float16* __restrict__ hf) {
  int bt = blockIdx.x;
  int t = bt & (TT - 1);
  int tid = threadIdx.x;
  int row = x[bt];
  float v0 = emb[(size_t)row * DM + tid]       + pos[(size_t)t * DM + tid];
  float v1 = emb[(size_t)row * DM + tid + 256] + pos[(size_t)t * DM + tid + 256];
  float s = v0 + v1, sq = v0 * v0 + v1 * v1;
  block_reduce2(s, sq);
  float mu  = s * (1.0f / DM);
  float var = sq * (1.0f / DM) - mu * mu;
  float rs  = rsqrtf(var + 1e-5f);
  float r0 = (v0 - mu) * rs, r1 = (v1 - mu) * rs;
  h[(size_t)bt * DM + tid] = r0;
  h[(size_t)bt * DM + tid + 256] = r1;
  hh[(size_t)bt * DM + tid] = bf16_bits(r0);
  hh[(size_t)bt * DM + tid + 256] = bf16_bits(r1);
  hf[(size_t)bt * DM + tid] = (_Float16)r0;
  hf[(size_t)bt * DM + tid + 256] = (_Float16)r1;
}

// ---------------- h = LN(h + add) ----------------
template<bool BF16ADD>
__global__ __launch_bounds__(256) void ln_residual_kernel(
    float* __restrict__ h, const void* __restrict__ add_,
    u16* __restrict__ hh, _Float16* __restrict__ hf) {
  int bt = blockIdx.x;
  int tid = threadIdx.x;
  float v0 = h[(size_t)bt * DM + tid];
  float v1 = h[(size_t)bt * DM + tid + 256];
  if (BF16ADD) {
    const u16* add = (const u16*)add_;
    v0 += bits_to_f32(add[(size_t)bt * DM + tid]);
    v1 += bits_to_f32(add[(size_t)bt * DM + tid + 256]);
  } else {
    const float* add = (const float*)add_;
    v0 += add[(size_t)bt * DM + tid];
    v1 += add[(size_t)bt * DM + tid + 256];
  }
  float s = v0 + v1, sq = v0 * v0 + v1 * v1;
  block_reduce2(s, sq);
  float mu  = s * (1.0f / DM);
  float var = sq * (1.0f / DM) - mu * mu;
  float rs  = rsqrtf(var + 1e-5f);
  float r0 = (v0 - mu) * rs, r1 = (v1 - mu) * rs;
  h[(size_t)bt * DM + tid] = r0;
  h[(size_t)bt * DM + tid + 256] = r1;
  hh[(size_t)bt * DM + tid] = bf16_bits(r0);
  hh[(size_t)bt * DM + tid + 256] = bf16_bits(r1);
  hf[(size_t)bt * DM + tid] = (_Float16)r0;
  hf[(size_t)bt * DM + tid + 256] = (_Float16)r1;
}

// ---------------- h transpose: h f32 [8192][512] -> hT bf16 [512][8192] -----
__global__ __launch_bounds__(256) void transpose_hT(
    const float* __restrict__ h, u16* __restrict__ hT) {
  __shared__ float T[64][65];
  int t0 = blockIdx.x * 64;   // token tile
  int d0 = blockIdx.y * 64;   // dm tile
  int tid = threadIdx.x;
  #pragma unroll
  for (int rep = 0; rep < 16; ++rep) {
    int idx = rep * 256 + tid;
    int i = idx >> 6, j = idx & 63;
    T[i][j] = h[(size_t)(t0 + i) * DM + d0 + j];
  }
  __syncthreads();
  #pragma unroll
  for (int rep = 0; rep < 16; ++rep) {
    int idx = rep * 256 + tid;
    int j = idx >> 6, i = idx & 63;
    hT[(size_t)(d0 + j) * (BB * TT) + t0 + i] = bf16_bits(T[i][j]);
  }
}

// ---------------- weight transpose + convert (compact 1D grid) ----------------
// slices: [0,64) wq->f16 wqkT[0,512), [64,128) wk->f16 wqkT[512,1024),
//         [128,640) wv->bf16 wvT2 [dv][h*512+c], [640,896) w0, [896,1152) w1
__global__ __launch_bounds__(256) void transpose_layer(
    const float* __restrict__ wq, const float* __restrict__ wk,
    const float* __restrict__ wv, const float* __restrict__ w0,
    const float* __restrict__ w1,
    _Float16* __restrict__ qkT, u16* __restrict__ vT2,
    u16* __restrict__ t0o, u16* __restrict__ t1o) {
  __shared__ float T[64][65];
  int t = blockIdx.x;
  const float* in;
  _Float16* of = nullptr;
  u16* ob = nullptr;
  int K, Nb;
  bool vmode = false;
  if (t < 64)       { in = wq; of = qkT;          K = 512;  Nb = 64; }
  else if (t < 128) { in = wk; of = qkT + 262144; K = 512;  Nb = 64;   t -= 64; }
  else if (t < 640) { in = wv; ob = vT2;          K = 512;  Nb = 512;  t -= 128; vmode = true; }
  else if (t < 896) { in = w0; ob = t0o;          K = 512;  Nb = 2048; t -= 640; }
  else              { in = w1; ob = t1o;          K = 2048; Nb = 512;  t -= 896; }
  int ntx = K >> 6;
  int k0 = (t % ntx) * 64, n0 = (t / ntx) * 64;
  int g = n0 / Nb;
  const float* src = in + (size_t)g * K * Nb + (n0 - g * Nb);
  int tid = threadIdx.x;
  #pragma unroll
  for (int rep = 0; rep < 16; ++rep) {
    int idx = rep * 256 + tid;
    int i = idx >> 6, j = idx & 63;
    T[i][j] = src[(size_t)(k0 + i) * Nb + j];
  }
  __syncthreads();
  #pragma unroll
  for (int rep = 0; rep < 16; ++rep) {
    int idx = rep * 256 + tid;
    int j = idx >> 6, i = idx & 63;
    float v = T[i][j];
    if (vmode) {
      // out[dv][h*512+c]: dv = n0-g*Nb+j, c = k0+i
      vT2[(size_t)(n0 - g * Nb + j) * (NH * DM) + g * Nb + k0 + i] = bf16_bits(v);
    } else if (of) {
      of[(size_t)(n0 + j) * K + k0 + i] = (_Float16)v;
    } else {
      ob[(size_t)(n0 + j) * K + k0 + i] = bf16_bits(v);
    }
  }
}

__global__ __launch_bounds__(256) void transpose_ue(
    const float* __restrict__ ue, u16* __restrict__ ueT) {
  __shared__ float T[64][65];
  int tid = threadIdx.x;
  int k0 = blockIdx.x * 64, n0 = blockIdx.y * 64;
  #pragma unroll
  for (int rep = 0; rep < 16; ++rep) {
    int idx = rep * 256 + tid;
    int i = idx >> 6, j = idx & 63;
    T[i][j] = ue[(size_t)(k0 + i) * ND + n0 + j];
  }
  __syncthreads();
  #pragma unroll
  for (int rep = 0; rep < 16; ++rep) {
    int idx = rep * 256 + tid;
    int j = idx >> 6, i = idx & 63;
    ueT[(size_t)(n0 + j) * DM + k0 + i] = bf16_bits(T[i][j]);
  }
}

// ---------------- bf16 MFMA GEMM: C[M][N] = A[M][K] @ Bt[N][K]^T ----------------
// MODE 1: bf16 bias+relu row-major   MODE 2: f32 row-major
// MODE 3: f32 + bias row-major       MODE 4: bf16 row-major
template<int MODE>
__global__ __launch_bounds__(256, 2) void gemm_mfma(
    const u16* __restrict__ A, const u16* __restrict__ Bt,
    const float* __restrict__ bias, void* __restrict__ Oo,
    int M, int N, int K) {
  __shared__ u16 As[2][8192];
  __shared__ u16 Bs[2][8192];
  int tid = threadIdx.x;
  int lane = tid & 63, w = tid >> 6;
  int l15 = lane & 15, g = lane >> 4;
  int m0 = blockIdx.x * 128, n0 = blockIdx.y * 128;
  int wr = w >> 1, wc = w & 1;
  int nt = K >> 6;

  f32x4 acc[4][4];
  #pragma unroll
  for (int i = 0; i < 4; ++i)
    #pragma unroll
    for (int j = 0; j < 4; ++j)
      #pragma unroll
      for (int r = 0; r < 4; ++r) acc[i][j][r] = 0.f;

  auto stage = [&](int t, int buf) {
    int k0 = t << 6;
    #pragma unroll
    for (int j = 0; j < 4; ++j) {
      int idx = j * 256 + tid;
      int row = idx >> 3, cs = (idx & 7) ^ (row & 7);
      gload16(A + (size_t)(m0 + row) * K + k0 + cs * 8, &As[buf][idx * 8]);
    }
    #pragma unroll
    for (int j = 0; j < 4; ++j) {
      int idx = j * 256 + tid;
      int row = idx >> 3, cs = (idx & 7) ^ (row & 7);
      gload16(Bt + (size_t)(n0 + row) * K + k0 + cs * 8, &Bs[buf][idx * 8]);
    }
  };

  stage(0, 0);
  for (int t = 0; t < nt; ++t) {
    int cur = t & 1;
    if (t + 1 < nt) {
      stage(t + 1, cur ^ 1);
      WAITVM(8);
    } else {
      WAITVM(0);
    }
    BAR();
    short8v af[4][2], bf[4][2];
    #pragma unroll
    for (int mi = 0; mi < 4; ++mi) {
      int row = wr * 64 + mi * 16 + l15;
      #pragma unroll
      for (int ks = 0; ks < 2; ++ks) {
        int ch = (ks * 4 + g) ^ (row & 7);
        af[mi][ks] = *(const short8v*)&As[cur][row * 64 + ch * 8];
      }
    }
    #pragma unroll
    for (int ni = 0; ni < 4; ++ni) {
      int row = wc * 64 + ni * 16 + l15;
      #pragma unroll
      for (int ks = 0; ks < 2; ++ks) {
        int ch = (ks * 4 + g) ^ (row & 7);
        bf[ni][ks] = *(const short8v*)&Bs[cur][row * 64 + ch * 8];
      }
    }
    __builtin_amdgcn_s_setprio(1);
    #pragma unroll
    for (int mi = 0; mi < 4; ++mi)
      #pragma unroll
      for (int ni = 0; ni < 4; ++ni) {
        acc[mi][ni] = MFMA16(af[mi][0], bf[ni][0], acc[mi][ni]);
        acc[mi][ni] = MFMA16(af[mi][1], bf[ni][1], acc[mi][ni]);
      }
    __builtin_amdgcn_s_setprio(0);
    BAR();
  }

  #pragma unroll
  for (int mi = 0; mi < 4; ++mi) {
    #pragma unroll
    for (int ni = 0; ni < 4; ++ni) {
      int mrow = m0 + wr * 64 + mi * 16 + g * 4;
      int ncol = n0 + wc * 64 + ni * 16 + l15;
      if (MODE == 1) {
        float bv = bias[ncol];
        #pragma unroll
        for (int r = 0; r < 4; ++r)
          ((u16*)Oo)[(size_t)(mrow + r) * N + ncol] =
              bf16_bits(fmaxf(acc[mi][ni][r] + bv, 0.f));
      } else if (MODE == 2) {
        #pragma unroll
        for (int r = 0; r < 4; ++r)
          ((float*)Oo)[(size_t)(mrow + r) * N + ncol] = acc[mi][ni][r];
      } else if (MODE == 3) {
        float bv = bias[ncol];
        #pragma unroll
        for (int r = 0; r < 4; ++r)
          ((float*)Oo)[(size_t)(mrow + r) * N + ncol] = acc[mi][ni][r] + bv;
      } else {
        #pragma unroll
        for (int r = 0; r < 4; ++r)
          ((u16*)Oo)[(size_t)(mrow + r) * N + ncol] = bf16_bits(acc[mi][ni][r]);
      }
    }
  }
}

// ---------------- f16 MFMA GEMM for fused Q+K -> f16 [b][h][t][dk] ----------
// Bt = wqkT [1024][512]; ncol<512 -> Q, else K (kf16 = qf16 + 4194304).
__global__ __launch_bounds__(256, 2) void gemm_qk_f16(
    const _Float16* __restrict__ A, const _Float16* __restrict__ Bt,
    _Float16* __restrict__ Oq, int K) {
  __shared__ _Float16 As[2][8192];
  __shared__ _Float16 Bs[2][8192];
  int tid = threadIdx.x;
  int lane = tid & 63, w = tid >> 6;
  int l15 = lane & 15, g = lane >> 4;
  int m0 = blockIdx.x * 128, n0 = blockIdx.y * 128;
  int wr = w >> 1, wc = w & 1;
  int nt = K >> 6;

  f32x4 acc[4][4];
  #pragma unroll
  for (int i = 0; i < 4; ++i)
    #pragma unroll
    for (int j = 0; j < 4; ++j)
      #pragma unroll
      for (int r = 0; r < 4; ++r) acc[i][j][r] = 0.f;

  auto stage = [&](int t, int buf) {
    int k0 = t << 6;
    #pragma unroll
    for (int j = 0; j < 4; ++j) {
      int idx = j * 256 + tid;
      int row = idx >> 3, cs = (idx & 7) ^ (row & 7);
      gload16(A + (size_t)(m0 + row) * K + k0 + cs * 8, &As[buf][idx * 8]);
    }
    #pragma unroll
    for (int j = 0; j < 4; ++j) {
      int idx = j * 256 + tid;
      int row = idx >> 3, cs = (idx & 7) ^ (row & 7);
      gload16(Bt + (size_t)(n0 + row) * K + k0 + cs * 8, &Bs[buf][idx * 8]);
    }
  };

  stage(0, 0);
  for (int t = 0; t < nt; ++t) {
    int cur = t & 1;
    if (t + 1 < nt) {
      stage(t + 1, cur ^ 1);
      WAITVM(8);
    } else {
      WAITVM(0);
    }
    BAR();
    f16x8 af[4][2], bf[4][2];
    #pragma unroll
    for (int mi = 0; mi < 4; ++mi) {
      int row = wr * 64 + mi * 16 + l15;
      #pragma unroll
      for (int ks = 0; ks < 2; ++ks) {
        int ch = (ks * 4 + g) ^ (row & 7);
        af[mi][ks] = *(const f16x8*)&As[cur][row * 64 + ch * 8];
      }
    }
    #pragma unroll
    for (int ni = 0; ni < 4; ++ni) {
      int row = wc * 64 + ni * 16 + l15;
      #pragma unroll
      for (int ks = 0; ks < 2; ++ks) {
        int ch = (ks * 4 + g) ^ (row & 7);
        bf[ni][ks] = *(const f16x8*)&Bs[cur][row * 64 + ch * 8];
      }
    }
    __builtin_amdgcn_s_setprio(1);
    #pragma unroll
    for (int mi = 0; mi < 4; ++mi)
      #pragma unroll
      for (int ni = 0; ni < 4; ++ni) {
        acc[mi][ni] = MFMAH(af[mi][0], bf[ni][0], acc[mi][ni]);
        acc[mi][ni] = MFMAH(af[mi][1], bf[ni][1], acc[mi][ni]);
      }
    __builtin_amdgcn_s_setprio(0);
    BAR();
  }

  #pragma unroll
  for (int mi = 0; mi < 4; ++mi) {
    #pragma unroll
    for (int ni = 0; ni < 4; ++ni) {
      int mrow = m0 + wr * 64 + mi * 16 + g * 4;
      int ncol = n0 + wc * 64 + ni * 16 + l15;
      _Float16* dst = Oq;
      int nc = ncol;
      if (nc >= 512) { dst = Oq + 4194304; nc -= 512; }
      int head = nc >> 6, dk = nc & (DK - 1);
      int bb = mrow >> 10;
      #pragma unroll
      for (int r = 0; r < 4; ++r) {
        int t = (mrow + r) & (TT - 1);
        dst[(((size_t)bb * NH + head) * TT + t) * DK + dk] = (_Float16)acc[mi][ni][r];
      }
    }
  }
}

// ---------------- MFMA flash attention v4: O' = softmax-num(QK^T) @ h ------
// PV B-operand is hT bf16 [512][8192] (8 MB, cache-hot, shared by all heads).
// K staged in LDS (dbuf, prefetch 1 ahead), f16 S, P dbuf in LDS, bf16 O'.
__global__ __launch_bounds__(256, 2) void attn_mfma_kernel(
    const _Float16* __restrict__ qp, const _Float16* __restrict__ kp,
    const u16* __restrict__ hT, u16* __restrict__ o) {
  __shared__ __align__(16) u16 Pl[2][64 * 64];
  __shared__ __align__(16) _Float16 Kl[2][64 * 64];
  __shared__ float rs_lds[64];

  int tid = threadIdx.x;
  int lane = tid & 63;
  int w = tid >> 6;
  int l15 = lane & 15, g = lane >> 4;
  int blk = blockIdx.x;
  int bh = blk & 63;
  int tt = 15 - (blk >> 6);          // heaviest causal tiles dispatch first
  int b = bh >> 3;

  if (tid < 64) rs_lds[tid] = 0.f;

  auto stageK = [&](int ot, int buf) {
    int ob = ot * 64;
    #pragma unroll
    for (int j = 0; j < 2; ++j) {
      int idx = j * 256 + tid;                 // 16B chunk id, 0..511
      int row = idx >> 3, cs = (idx & 7) ^ (row & 7);
      gload16(kp + ((size_t)bh * TT + ob + row) * DK + cs * 8, &Kl[buf][idx * 8]);
    }
  };

  size_t qbase = (((size_t)bh * TT) + tt * 64 + w * 16 + l15) * DK + g * 8;
  f16x8 qf[2];
  qf[0] = *(const f16x8*)(qp + qbase);
  qf[1] = *(const f16x8*)(qp + qbase + 32);

  f32x4 oacc[4][8];
  #pragma unroll
  for (int qt = 0; qt < 4; ++qt)
    #pragma unroll
    for (int dv = 0; dv < 8; ++dv)
      #pragma unroll
      for (int r = 0; r < 4; ++r) oacc[qt][dv][r] = 0.f;

  stageK(0, 0);
  WAITVM(0);
  __syncthreads();

  for (int ot = 0; ot <= tt; ++ot) {
    int ob = ot * 64;
    bool diag = (ot == tt);
    int buf = ot & 1;
    // prefetch next K tile (drained by this tile's vmcnt(0)+barrier)
    if (ot < tt) stageK(ot + 1, buf ^ 1);
    // S = Q K^T from LDS K (swizzled ds_read_b128)
    f32x4 sacc[4];
    #pragma unroll
    for (int ct = 0; ct < 4; ++ct)
      #pragma unroll
      for (int r = 0; r < 4; ++r) sacc[ct][r] = 0.f;
    __builtin_amdgcn_s_setprio(1);
    #pragma unroll
    for (int ct = 0; ct < 4; ++ct) {
      int row = ct * 16 + l15;
      f16x8 k0 = *(const f16x8*)&Kl[buf][row * 64 + ((g) ^ (row & 7)) * 8];
      f16x8 k1 = *(const f16x8*)&Kl[buf][row * 64 + ((4 + g) ^ (row & 7)) * 8];
      sacc[ct] = MFMAH(qf[0], k0, sacc[ct]);
      sacc[ct] = MFMAH(qf[1], k1, sacc[ct]);
    }
    __builtin_amdgcn_s_setprio(0);
    // hT-operand ks=0 loads (independent of P) issued before exp
    size_t vbase = ((size_t)(w * 128 + l15)) * (BB * TT) + b * TT + ob + g * 8;
    short8v vf0[8];
    #pragma unroll
    for (int dv = 0; dv < 8; ++dv)
      vf0[dv] = *(const short8v*)(hT + vbase + (size_t)dv * 16 * (BB * TT));
    // exp + mask + row-sum + P->LDS (bf16, XOR-swizzled)
    float psum[4] = {0.f, 0.f, 0.f, 0.f};
    #pragma unroll
    for (int ct = 0; ct < 4; ++ct) {
      #pragma unroll
      for (int r = 0; r < 4; ++r) {
        float s = sacc[ct][r];
        float p = __expf(fminf(s, 50.f));
        if (diag && (ct * 16 + l15 > w * 16 + g * 4 + r)) p = 0.f;
        psum[r] += p;
        int q = w * 16 + g * 4 + r;
        int byte = (q * 128 + (ct * 16 + l15) * 2) ^ ((q & 7) << 4);
        *(u16*)((char*)Pl[buf] + byte) = bf16_bits(p);
      }
    }
    #pragma unroll
    for (int r = 0; r < 4; ++r) {
      float v = psum[r];
      v += __shfl_xor(v, 1, 16);
      v += __shfl_xor(v, 2, 16);
      v += __shfl_xor(v, 4, 16);
      v += __shfl_xor(v, 8, 16);
      if (l15 == 0) rs_lds[w * 16 + g * 4 + r] += v;
    }
    WAITVM(0);     // drain K(ot+1) stage + vf0
    BAR();
    // PV: issue ks=1 hT loads first, then compute ks=0 with vf0
    short8v vf1[8];
    #pragma unroll
    for (int dv = 0; dv < 8; ++dv)
      vf1[dv] = *(const short8v*)(hT + vbase + 32 + (size_t)dv * 16 * (BB * TT));
    short8v pf[4];
    #pragma unroll
    for (int qt = 0; qt < 4; ++qt) {
      int q = qt * 16 + l15;
      int byte = (q * 128 + g * 16) ^ ((q & 7) << 4);
      pf[qt] = *(short8v*)((char*)Pl[buf] + byte);
    }
    __builtin_amdgcn_s_setprio(1);
    #pragma unroll
    for (int dv = 0; dv < 8; ++dv)
      #pragma unroll
      for (int qt = 0; qt < 4; ++qt)
        oacc[qt][dv] = MFMA16(pf[qt], vf0[dv], oacc[qt][dv]);
    __builtin_amdgcn_s_setprio(0);
    #pragma unroll
    for (int qt = 0; qt < 4; ++qt) {
      int q = qt * 16 + l15;
      int byte = (q * 128 + 64 + g * 16) ^ ((q & 7) << 4);
      pf[qt] = *(short8v*)((char*)Pl[buf] + byte);
    }
    __builtin_amdgcn_s_setprio(1);
    #pragma unroll
    for (int dv = 0; dv < 8; ++dv)
      #pragma unroll
      for (int qt = 0; qt < 4; ++qt)
        oacc[qt][dv] = MFMA16(pf[qt], vf1[dv], oacc[qt][dv]);
    __builtin_amdgcn_s_setprio(0);
  }
  // epilogue: normalize, write O' bf16 [bt][h*512+dm]
  __syncthreads();
  int hh2 = bh & 7;
  #pragma unroll
  for (int qt = 0; qt < 4; ++qt) {
    #pragma unroll
    for (int r = 0; r < 4; ++r) {
      int q = qt * 16 + g * 4 + r;
      float rs = 1.0f / (rs_lds[q] + 1e-10f);
      size_t rowbase = ((size_t)(b * TT + tt * 64 + q)) * (NH * DM) + hh2 * DM + w * 128 + l15;
      #pragma unroll
      for (int dv = 0; dv < 8; ++dv)
        o[rowbase + dv * 16] = bf16_bits(oacc[qt][dv][r] * rs);
    }
  }
}

extern "C" void kernel_launch(void* const* d_in, const int* in_sizes, int n_in,
                              void* d_out, int out_size, void* d_ws, size_t ws_size,
                              hipStream_t stream) {
  (void)in_sizes; (void)n_in; (void)out_size; (void)ws_size;
  const int*   x   = (const int*)d_in[0];
  const float* emb = (const float*)d_in[3];
  const float* pos = (const float*)d_in[4];
  const float* wq  = (const float*)d_in[5];
  const float* wk  = (const float*)d_in[6];
  const float* wv  = (const float*)d_in[7];
  const float* m0  = (const float*)d_in[8];
  const float* mb  = (const float*)d_in[9];
  const float* m1  = (const float*)d_in[10];
  const float* ue  = (const float*)d_in[11];
  const float* ub  = (const float*)d_in[12];
  float* out = (float*)d_out;
  float* ws  = (float*)d_ws;

  const int M = BB * TT;

  // ws layout: h f32 | hh bf16 | hf16 f16 | yb f32 | ueT bf16
  float*    h    = ws;
  u16*      hh   = (u16*)(ws + 4194304);
  _Float16* hf16 = (_Float16*)(ws + 6291456);
  float*    yb   = ws + 8388608;
  u16*      ueT  = (u16*)(ws + 12582912);

  // d_out scratch layout (u16 units):
  // hT [0,4.2M) | hid [4.2M,21.0M) | vsum [21.0M,25.2M) | qf16 [33.5M,+4.2M)
  // | kf16 [37.7M,+4.2M) | wT [41.9M,...) | Ob [67.1M,+33.5M)
  u16* outus = (u16*)d_out;
  u16* hT   = outus;
  u16* hid  = outus + 4194304;
  u16* vsum = outus + 20971520;
  _Float16* qf16 = (_Float16*)(outus + 33554432);
  u16* wT = outus + 41943040;
  _Float16* wqkT = (_Float16*)wT;                // 524288 f16 (q rows then k rows)
  u16* wvT2 = wT + 524288;                       // 2097152 (dv x 4096)
  u16* w0T  = wT + 2621440;                      // 1048576
  u16* w1T  = wT + 3670016;                      // 1048576
  u16* Ob   = outus + 67108864;                  // bf16 [bt][h*512+dm]

  embed_ln_kernel<<<M, 256, 0, stream>>>(x, emb, pos, h, hh, hf16);
  transpose_hT<<<dim3(128, 8), 256, 0, stream>>>(h, hT);

  for (int l = 0; l < NL; ++l) {
    transpose_layer<<<1152, 256, 0, stream>>>(
        wq + (size_t)l * NH * DM * DK, wk + (size_t)l * NH * DM * DK,
        wv + (size_t)l * NH * DM * DM, m0 + (size_t)l * DM * DH,
        m1 + (size_t)l * DH * DM,
        wqkT, wvT2, w0T, w1T);
    gemm_qk_f16<<<dim3(64, 8), 256, 0, stream>>>(hf16, wqkT, qf16, DM);
    attn_mfma_kernel<<<BB * NH * (TT / 64), 256, 0, stream>>>(
        qf16, qf16 + 4194304, hT, Ob);
    gemm_mfma<4><<<dim3(64, 4), 256, 0, stream>>>(Ob, wvT2, nullptr, vsum, M, DM, NH * DM);
    ln_residual_kernel<true><<<M, 256, 0, stream>>>(h, vsum, hh, hf16);
    gemm_mfma<1><<<dim3(64, 16), 256, 0, stream>>>(hh, w0T, mb + (size_t)l * DH, hid, M, DH, DM);
    gemm_mfma<2><<<dim3(64, 4), 256, 0, stream>>>(hid, w1T, nullptr, yb, M, DM, DH);
    ln_residual_kernel<false><<<M, 256, 0, stream>>>(h, yb, hh, hf16);
    if (l + 1 < NL)
      transpose_hT<<<dim3(128, 8), 256, 0, stream>>>(h, hT);
  }
  transpose_ue<<<dim3(8, 128), 256, 0, stream>>>(ue, ueT);
  gemm_mfma<3><<<dim3(64, 64), 256, 0, stream>>>(hh, ueT, ub, out, M, ND, DM);
}

// Round 7
// 2203.735 us; speedup vs baseline: 1.0687x; 1.0687x over previous
//
#include <hip/hip_runtime.h>
#include <hip/hip_bf16.h>

#define BB 8
#define TT 1024
#define DM 512
#define NH 8
#define DK 64
#define DH 2048
#define NL 8
#define ND 8192

typedef __attribute__((ext_vector_type(8))) short short8v;
typedef __attribute__((ext_vector_type(8))) _Float16 f16x8;
typedef __attribute__((ext_vector_type(4))) float f32x4;
typedef __attribute__((ext_vector_type(4))) unsigned short ushort4v;
typedef unsigned short u16;

#define MFMA16(a, b, c) __builtin_amdgcn_mfma_f32_16x16x32_bf16(a, b, c, 0, 0, 0)
#define MFMAH(a, b, c)  __builtin_amdgcn_mfma_f32_16x16x32_f16(a, b, c, 0, 0, 0)

__device__ __forceinline__ u16 bf16_bits(float f) {
  union { __hip_bfloat16 h; u16 u; } cv;
  cv.h = __float2bfloat16(f);
  return cv.u;
}
__device__ __forceinline__ float bits_to_f32(u16 u) {
  union { __hip_bfloat16 h; u16 u; } cv;
  cv.u = u;
  return __bfloat162float(cv.h);
}

__device__ __forceinline__ void gload16(const void* g, void* l) {
  __builtin_amdgcn_global_load_lds(
      (const __attribute__((address_space(1))) unsigned int*)g,
      (__attribute__((address_space(3))) unsigned int*)l, 16, 0, 0);
}

#define WAITVM(N) asm volatile("s_waitcnt vmcnt(" #N ")" ::: "memory")
#define WAITLGKM() asm volatile("s_waitcnt lgkmcnt(0)" ::: "memory")
#define BAR() { __builtin_amdgcn_s_barrier(); asm volatile("" ::: "memory"); }

// ---------------- block reduce (256 threads, 2 accumulators) ----------------
__device__ __forceinline__ void block_reduce2(float& a, float& b) {
  #pragma unroll
  for (int off = 32; off > 0; off >>= 1) {
    a += __shfl_down(a, off, 64);
    b += __shfl_down(b, off, 64);
  }
  __shared__ float sa[4], sb[4];
  int w = threadIdx.x >> 6;
  if ((threadIdx.x & 63) == 0) { sa[w] = a; sb[w] = b; }
  __syncthreads();
  if (threadIdx.x == 0) {
    sa[0] = sa[0] + sa[1] + sa[2] + sa[3];
    sb[0] = sb[0] + sb[1] + sb[2] + sb[3];
  }
  __syncthreads();
  a = sa[0]; b = sb[0];
}

// ---------------- embedding + LN ----------------
__global__ __launch_bounds__(256) void embed_ln_kernel(
    const int* __restrict__ x, const float* __restrict__ emb,
    const float* __restrict__ pos, float* __restrict__ h,
    u16* __restrict__ hh, _Float16* __restrict__ hf) {
  int bt = blockIdx.x;
  int t = bt & (TT - 1);
  int tid = threadIdx.x;
  int row = x[bt];
  float v0 = emb[(size_t)row * DM + tid]       + pos[(size_t)t * DM + tid];
  float v1 = emb[(size_t)row * DM + tid + 256] + pos[(size_t)t * DM + tid + 256];
  float s = v0 + v1, sq = v0 * v0 + v1 * v1;
  block_reduce2(s, sq);
  float mu  = s * (1.0f / DM);
  float var = sq * (1.0f / DM) - mu * mu;
  float rs  = rsqrtf(var + 1e-5f);
  float r0 = (v0 - mu) * rs, r1 = (v1 - mu) * rs;
  h[(size_t)bt * DM + tid] = r0;
  h[(size_t)bt * DM + tid + 256] = r1;
  hh[(size_t)bt * DM + tid] = bf16_bits(r0);
  hh[(size_t)bt * DM + tid + 256] = bf16_bits(r1);
  hf[(size_t)bt * DM + tid] = (_Float16)r0;
  hf[(size_t)bt * DM + tid + 256] = (_Float16)r1;
}

// ---------------- h = LN(h + add) ----------------
template<bool BF16ADD>
__global__ __launch_bounds__(256) void ln_residual_kernel(
    float* __restrict__ h, const void* __restrict__ add_,
    u16* __restrict__ hh, _Float16* __restrict__ hf) {
  int bt = blockIdx.x;
  int tid = threadIdx.x;
  float v0 = h[(size_t)bt * DM + tid];
  float v1 = h[(size_t)bt * DM + tid + 256];
  if (BF16ADD) {
    const u16* add = (const u16*)add_;
    v0 += bits_to_f32(add[(size_t)bt * DM + tid]);
    v1 += bits_to_f32(add[(size_t)bt * DM + tid + 256]);
  } else {
    const float* add = (const float*)add_;
    v0 += add[(size_t)bt * DM + tid];
    v1 += add[(size_t)bt * DM + tid + 256];
  }
  float s = v0 + v1, sq = v0 * v0 + v1 * v1;
  block_reduce2(s, sq);
  float mu  = s * (1.0f / DM);
  float var = sq * (1.0f / DM) - mu * mu;
  float rs  = rsqrtf(var + 1e-5f);
  float r0 = (v0 - mu) * rs, r1 = (v1 - mu) * rs;
  h[(size_t)bt * DM + tid] = r0;
  h[(size_t)bt * DM + tid + 256] = r1;
  hh[(size_t)bt * DM + tid] = bf16_bits(r0);
  hh[(size_t)bt * DM + tid + 256] = bf16_bits(r1);
  hf[(size_t)bt * DM + tid] = (_Float16)r0;
  hf[(size_t)bt * DM + tid + 256] = (_Float16)r1;
}

// ---------------- h transpose: h f32 [8192][512] -> hT bf16 [512][8192] -----
__global__ __launch_bounds__(256) void transpose_hT(
    const float* __restrict__ h, u16* __restrict__ hT) {
  __shared__ float T[64][65];
  int t0 = blockIdx.x * 64;   // token tile
  int d0 = blockIdx.y * 64;   // dm tile
  int tid = threadIdx.x;
  #pragma unroll
  for (int rep = 0; rep < 16; ++rep) {
    int idx = rep * 256 + tid;
    int i = idx >> 6, j = idx & 63;
    T[i][j] = h[(size_t)(t0 + i) * DM + d0 + j];
  }
  __syncthreads();
  #pragma unroll
  for (int rep = 0; rep < 16; ++rep) {
    int idx = rep * 256 + tid;
    int j = idx >> 6, i = idx & 63;
    hT[(size_t)(d0 + j) * (BB * TT) + t0 + i] = bf16_bits(T[i][j]);
  }
}

// ---------------- weight transpose + convert (compact 1D grid) ----------------
// slices: [0,64) wq->f16 wqkT[0,512), [64,128) wk->f16 wqkT[512,1024),
//         [128,640) wv->bf16 wvT2 [dv][h*512+c], [640,896) w0, [896,1152) w1
__global__ __launch_bounds__(256) void transpose_layer(
    const float* __restrict__ wq, const float* __restrict__ wk,
    const float* __restrict__ wv, const float* __restrict__ w0,
    const float* __restrict__ w1,
    _Float16* __restrict__ qkT, u16* __restrict__ vT2,
    u16* __restrict__ t0o, u16* __restrict__ t1o) {
  __shared__ float T[64][65];
  int t = blockIdx.x;
  const float* in;
  _Float16* of = nullptr;
  u16* ob = nullptr;
  int K, Nb;
  bool vmode = false;
  if (t < 64)       { in = wq; of = qkT;          K = 512;  Nb = 64; }
  else if (t < 128) { in = wk; of = qkT + 262144; K = 512;  Nb = 64;   t -= 64; }
  else if (t < 640) { in = wv; ob = vT2;          K = 512;  Nb = 512;  t -= 128; vmode = true; }
  else if (t < 896) { in = w0; ob = t0o;          K = 512;  Nb = 2048; t -= 640; }
  else              { in = w1; ob = t1o;          K = 2048; Nb = 512;  t -= 896; }
  int ntx = K >> 6;
  int k0 = (t % ntx) * 64, n0 = (t / ntx) * 64;
  int g = n0 / Nb;
  const float* src = in + (size_t)g * K * Nb + (n0 - g * Nb);
  int tid = threadIdx.x;
  #pragma unroll
  for (int rep = 0; rep < 16; ++rep) {
    int idx = rep * 256 + tid;
    int i = idx >> 6, j = idx & 63;
    T[i][j] = src[(size_t)(k0 + i) * Nb + j];
  }
  __syncthreads();
  #pragma unroll
  for (int rep = 0; rep < 16; ++rep) {
    int idx = rep * 256 + tid;
    int j = idx >> 6, i = idx & 63;
    float v = T[i][j];
    if (vmode) {
      vT2[(size_t)(n0 - g * Nb + j) * (NH * DM) + g * Nb + k0 + i] = bf16_bits(v);
    } else if (of) {
      of[(size_t)(n0 + j) * K + k0 + i] = (_Float16)v;
    } else {
      ob[(size_t)(n0 + j) * K + k0 + i] = bf16_bits(v);
    }
  }
}

__global__ __launch_bounds__(256) void transpose_ue(
    const float* __restrict__ ue, u16* __restrict__ ueT) {
  __shared__ float T[64][65];
  int tid = threadIdx.x;
  int k0 = blockIdx.x * 64, n0 = blockIdx.y * 64;
  #pragma unroll
  for (int rep = 0; rep < 16; ++rep) {
    int idx = rep * 256 + tid;
    int i = idx >> 6, j = idx & 63;
    T[i][j] = ue[(size_t)(k0 + i) * ND + n0 + j];
  }
  __syncthreads();
  #pragma unroll
  for (int rep = 0; rep < 16; ++rep) {
    int idx = rep * 256 + tid;
    int j = idx >> 6, i = idx & 63;
    ueT[(size_t)(n0 + j) * DM + k0 + i] = bf16_bits(T[i][j]);
  }
}

// ---------------- bf16 MFMA GEMM 128x128: C[M][N] = A[M][K] @ Bt[N][K]^T ----
// MODE 1: bf16 bias+relu row-major   MODE 2: f32 row-major
// MODE 3: f32 + bias row-major       MODE 4: bf16 row-major
template<int MODE>
__global__ __launch_bounds__(256, 2) void gemm_mfma(
    const u16* __restrict__ A, const u16* __restrict__ Bt,
    const float* __restrict__ bias, void* __restrict__ Oo,
    int M, int N, int K) {
  __shared__ u16 As[2][8192];
  __shared__ u16 Bs[2][8192];
  int tid = threadIdx.x;
  int lane = tid & 63, w = tid >> 6;
  int l15 = lane & 15, g = lane >> 4;
  int m0 = blockIdx.x * 128, n0 = blockIdx.y * 128;
  int wr = w >> 1, wc = w & 1;
  int nt = K >> 6;

  f32x4 acc[4][4];
  #pragma unroll
  for (int i = 0; i < 4; ++i)
    #pragma unroll
    for (int j = 0; j < 4; ++j)
      #pragma unroll
      for (int r = 0; r < 4; ++r) acc[i][j][r] = 0.f;

  auto stage = [&](int t, int buf) {
    int k0 = t << 6;
    #pragma unroll
    for (int j = 0; j < 4; ++j) {
      int idx = j * 256 + tid;
      int row = idx >> 3, cs = (idx & 7) ^ (row & 7);
      gload16(A + (size_t)(m0 + row) * K + k0 + cs * 8, &As[buf][idx * 8]);
    }
    #pragma unroll
    for (int j = 0; j < 4; ++j) {
      int idx = j * 256 + tid;
      int row = idx >> 3, cs = (idx & 7) ^ (row & 7);
      gload16(Bt + (size_t)(n0 + row) * K + k0 + cs * 8, &Bs[buf][idx * 8]);
    }
  };

  stage(0, 0);
  for (int t = 0; t < nt; ++t) {
    int cur = t & 1;
    if (t + 1 < nt) {
      stage(t + 1, cur ^ 1);
      WAITVM(8);
    } else {
      WAITVM(0);
    }
    BAR();
    short8v af[4][2], bf[4][2];
    #pragma unroll
    for (int mi = 0; mi < 4; ++mi) {
      int row = wr * 64 + mi * 16 + l15;
      #pragma unroll
      for (int ks = 0; ks < 2; ++ks) {
        int ch = (ks * 4 + g) ^ (row & 7);
        af[mi][ks] = *(const short8v*)&As[cur][row * 64 + ch * 8];
      }
    }
    #pragma unroll
    for (int ni = 0; ni < 4; ++ni) {
      int row = wc * 64 + ni * 16 + l15;
      #pragma unroll
      for (int ks = 0; ks < 2; ++ks) {
        int ch = (ks * 4 + g) ^ (row & 7);
        bf[ni][ks] = *(const short8v*)&Bs[cur][row * 64 + ch * 8];
      }
    }
    __builtin_amdgcn_s_setprio(1);
    #pragma unroll
    for (int mi = 0; mi < 4; ++mi)
      #pragma unroll
      for (int ni = 0; ni < 4; ++ni) {
        acc[mi][ni] = MFMA16(af[mi][0], bf[ni][0], acc[mi][ni]);
        acc[mi][ni] = MFMA16(af[mi][1], bf[ni][1], acc[mi][ni]);
      }
    __builtin_amdgcn_s_setprio(0);
    BAR();
  }

  #pragma unroll
  for (int mi = 0; mi < 4; ++mi) {
    #pragma unroll
    for (int ni = 0; ni < 4; ++ni) {
      int mrow = m0 + wr * 64 + mi * 16 + g * 4;
      int ncol = n0 + wc * 64 + ni * 16 + l15;
      if (MODE == 1) {
        float bv = bias[ncol];
        #pragma unroll
        for (int r = 0; r < 4; ++r)
          ((u16*)Oo)[(size_t)(mrow + r) * N + ncol] =
              bf16_bits(fmaxf(acc[mi][ni][r] + bv, 0.f));
      } else if (MODE == 2) {
        #pragma unroll
        for (int r = 0; r < 4; ++r)
          ((float*)Oo)[(size_t)(mrow + r) * N + ncol] = acc[mi][ni][r];
      } else if (MODE == 3) {
        float bv = bias[ncol];
        #pragma unroll
        for (int r = 0; r < 4; ++r)
          ((float*)Oo)[(size_t)(mrow + r) * N + ncol] = acc[mi][ni][r] + bv;
      } else {
        #pragma unroll
        for (int r = 0; r < 4; ++r)
          ((u16*)Oo)[(size_t)(mrow + r) * N + ncol] = bf16_bits(acc[mi][ni][r]);
      }
    }
  }
}

// ---------------- bf16 MFMA GEMM 128x64 tile (for N=512 GEMMs, 2 blocks/CU) --
// MODE 2: f32 row-major   MODE 4: bf16 row-major
template<int MODE>
__global__ __launch_bounds__(256, 2) void gemm_n64(
    const u16* __restrict__ A, const u16* __restrict__ Bt,
    void* __restrict__ Oo, int M, int N, int K) {
  __shared__ u16 As[2][8192];   // 128 x 64
  __shared__ u16 Bs[2][4096];   //  64 x 64
  int tid = threadIdx.x;
  int lane = tid & 63, w = tid >> 6;
  int l15 = lane & 15, g = lane >> 4;
  int m0 = blockIdx.x * 128, n0 = blockIdx.y * 64;
  int wr = w >> 1, wc = w & 1;
  int nt = K >> 6;

  f32x4 acc[4][2];
  #pragma unroll
  for (int i = 0; i < 4; ++i)
    #pragma unroll
    for (int j = 0; j < 2; ++j)
      #pragma unroll
      for (int r = 0; r < 4; ++r) acc[i][j][r] = 0.f;

  auto stage = [&](int t, int buf) {
    int k0 = t << 6;
    #pragma unroll
    for (int j = 0; j < 4; ++j) {
      int idx = j * 256 + tid;
      int row = idx >> 3, cs = (idx & 7) ^ (row & 7);
      gload16(A + (size_t)(m0 + row) * K + k0 + cs * 8, &As[buf][idx * 8]);
    }
    #pragma unroll
    for (int j = 0; j < 2; ++j) {
      int idx = j * 256 + tid;
      int row = idx >> 3, cs = (idx & 7) ^ (row & 7);
      gload16(Bt + (size_t)(n0 + row) * K + k0 + cs * 8, &Bs[buf][idx * 8]);
    }
  };

  stage(0, 0);
  for (int t = 0; t < nt; ++t) {
    int cur = t & 1;
    if (t + 1 < nt) {
      stage(t + 1, cur ^ 1);
      WAITVM(6);
    } else {
      WAITVM(0);
    }
    BAR();
    short8v af[4][2], bf[2][2];
    #pragma unroll
    for (int mi = 0; mi < 4; ++mi) {
      int row = wr * 64 + mi * 16 + l15;
      #pragma unroll
      for (int ks = 0; ks < 2; ++ks) {
        int ch = (ks * 4 + g) ^ (row & 7);
        af[mi][ks] = *(const short8v*)&As[cur][row * 64 + ch * 8];
      }
    }
    #pragma unroll
    for (int ni = 0; ni < 2; ++ni) {
      int row = wc * 32 + ni * 16 + l15;
      #pragma unroll
      for (int ks = 0; ks < 2; ++ks) {
        int ch = (ks * 4 + g) ^ (row & 7);
        bf[ni][ks] = *(const short8v*)&Bs[cur][row * 64 + ch * 8];
      }
    }
    __builtin_amdgcn_s_setprio(1);
    #pragma unroll
    for (int mi = 0; mi < 4; ++mi)
      #pragma unroll
      for (int ni = 0; ni < 2; ++ni) {
        acc[mi][ni] = MFMA16(af[mi][0], bf[ni][0], acc[mi][ni]);
        acc[mi][ni] = MFMA16(af[mi][1], bf[ni][1], acc[mi][ni]);
      }
    __builtin_amdgcn_s_setprio(0);
    BAR();
  }

  #pragma unroll
  for (int mi = 0; mi < 4; ++mi) {
    #pragma unroll
    for (int ni = 0; ni < 2; ++ni) {
      int mrow = m0 + wr * 64 + mi * 16 + g * 4;
      int ncol = n0 + wc * 32 + ni * 16 + l15;
      if (MODE == 2) {
        #pragma unroll
        for (int r = 0; r < 4; ++r)
          ((float*)Oo)[(size_t)(mrow + r) * N + ncol] = acc[mi][ni][r];
      } else {
        #pragma unroll
        for (int r = 0; r < 4; ++r)
          ((u16*)Oo)[(size_t)(mrow + r) * N + ncol] = bf16_bits(acc[mi][ni][r]);
      }
    }
  }
}

// ---------------- f16 MFMA GEMM for fused Q+K -> f16 [b][h][t][dk] ----------
// Bt = wqkT [1024][512]; ncol<512 -> Q, else K (kf16 = qf16 + 4194304).
__global__ __launch_bounds__(256, 2) void gemm_qk_f16(
    const _Float16* __restrict__ A, const _Float16* __restrict__ Bt,
    _Float16* __restrict__ Oq, int K) {
  __shared__ _Float16 As[2][8192];
  __shared__ _Float16 Bs[2][8192];
  int tid = threadIdx.x;
  int lane = tid & 63, w = tid >> 6;
  int l15 = lane & 15, g = lane >> 4;
  int m0 = blockIdx.x * 128, n0 = blockIdx.y * 128;
  int wr = w >> 1, wc = w & 1;
  int nt = K >> 6;

  f32x4 acc[4][4];
  #pragma unroll
  for (int i = 0; i < 4; ++i)
    #pragma unroll
    for (int j = 0; j < 4; ++j)
      #pragma unroll
      for (int r = 0; r < 4; ++r) acc[i][j][r] = 0.f;

  auto stage = [&](int t, int buf) {
    int k0 = t << 6;
    #pragma unroll
    for (int j = 0; j < 4; ++j) {
      int idx = j * 256 + tid;
      int row = idx >> 3, cs = (idx & 7) ^ (row & 7);
      gload16(A + (size_t)(m0 + row) * K + k0 + cs * 8, &As[buf][idx * 8]);
    }
    #pragma unroll
    for (int j = 0; j < 4; ++j) {
      int idx = j * 256 + tid;
      int row = idx >> 3, cs = (idx & 7) ^ (row & 7);
      gload16(Bt + (size_t)(n0 + row) * K + k0 + cs * 8, &Bs[buf][idx * 8]);
    }
  };

  stage(0, 0);
  for (int t = 0; t < nt; ++t) {
    int cur = t & 1;
    if (t + 1 < nt) {
      stage(t + 1, cur ^ 1);
      WAITVM(8);
    } else {
      WAITVM(0);
    }
    BAR();
    f16x8 af[4][2], bf[4][2];
    #pragma unroll
    for (int mi = 0; mi < 4; ++mi) {
      int row = wr * 64 + mi * 16 + l15;
      #pragma unroll
      for (int ks = 0; ks < 2; ++ks) {
        int ch = (ks * 4 + g) ^ (row & 7);
        af[mi][ks] = *(const f16x8*)&As[cur][row * 64 + ch * 8];
      }
    }
    #pragma unroll
    for (int ni = 0; ni < 4; ++ni) {
      int row = wc * 64 + ni * 16 + l15;
      #pragma unroll
      for (int ks = 0; ks < 2; ++ks) {
        int ch = (ks * 4 + g) ^ (row & 7);
        bf[ni][ks] = *(const f16x8*)&Bs[cur][row * 64 + ch * 8];
      }
    }
    __builtin_amdgcn_s_setprio(1);
    #pragma unroll
    for (int mi = 0; mi < 4; ++mi)
      #pragma unroll
      for (int ni = 0; ni < 4; ++ni) {
        acc[mi][ni] = MFMAH(af[mi][0], bf[ni][0], acc[mi][ni]);
        acc[mi][ni] = MFMAH(af[mi][1], bf[ni][1], acc[mi][ni]);
      }
    __builtin_amdgcn_s_setprio(0);
    BAR();
  }

  #pragma unroll
  for (int mi = 0; mi < 4; ++mi) {
    #pragma unroll
    for (int ni = 0; ni < 4; ++ni) {
      int mrow = m0 + wr * 64 + mi * 16 + g * 4;
      int ncol = n0 + wc * 64 + ni * 16 + l15;
      _Float16* dst = Oq;
      int nc = ncol;
      if (nc >= 512) { dst = Oq + 4194304; nc -= 512; }
      int head = nc >> 6, dk = nc & (DK - 1);
      int bb = mrow >> 10;
      #pragma unroll
      for (int r = 0; r < 4; ++r) {
        int t = (mrow + r) & (TT - 1);
        dst[(((size_t)bb * NH + head) * TT + t) * DK + dk] = (_Float16)acc[mi][ni][r];
      }
    }
  }
}

// ---------------- MFMA flash attention v5: O' = softmax-num(QK^T) @ h ------
// PV B-operand is hT bf16 [512][8192] (8 MB, cache-hot, shared by all heads).
// K staged in LDS (dbuf, prefetch 1 ahead), counted vmcnt(8) (only the K-stage
// ops must drain before the barrier; vf0 loads stay in flight).
__global__ __launch_bounds__(256, 2) void attn_mfma_kernel(
    const _Float16* __restrict__ qp, const _Float16* __restrict__ kp,
    const u16* __restrict__ hT, u16* __restrict__ o) {
  __shared__ __align__(16) u16 Pl[2][64 * 64];
  __shared__ __align__(16) _Float16 Kl[2][64 * 64];
  __shared__ float rs_lds[64];

  int tid = threadIdx.x;
  int lane = tid & 63;
  int w = tid >> 6;
  int l15 = lane & 15, g = lane >> 4;
  int blk = blockIdx.x;
  int bh = blk & 63;
  int tt = 15 - (blk >> 6);          // heaviest causal tiles dispatch first
  int b = bh >> 3;

  if (tid < 64) rs_lds[tid] = 0.f;

  auto stageK = [&](int ot, int buf) {
    int ob = ot * 64;
    #pragma unroll
    for (int j = 0; j < 2; ++j) {
      int idx = j * 256 + tid;                 // 16B chunk id, 0..511
      int row = idx >> 3, cs = (idx & 7) ^ (row & 7);
      gload16(kp + ((size_t)bh * TT + ob + row) * DK + cs * 8, &Kl[buf][idx * 8]);
    }
  };

  size_t qbase = (((size_t)bh * TT) + tt * 64 + w * 16 + l15) * DK + g * 8;
  f16x8 qf[2];
  qf[0] = *(const f16x8*)(qp + qbase);
  qf[1] = *(const f16x8*)(qp + qbase + 32);

  f32x4 oacc[4][8];
  #pragma unroll
  for (int qt = 0; qt < 4; ++qt)
    #pragma unroll
    for (int dv = 0; dv < 8; ++dv)
      #pragma unroll
      for (int r = 0; r < 4; ++r) oacc[qt][dv][r] = 0.f;

  stageK(0, 0);
  WAITVM(0);
  __syncthreads();

  for (int ot = 0; ot <= tt; ++ot) {
    int ob = ot * 64;
    bool diag = (ot == tt);
    int buf = ot & 1;
    // prefetch next K tile (drained by the counted vmcnt before this barrier)
    if (ot < tt) stageK(ot + 1, buf ^ 1);
    // S = Q K^T from LDS K (swizzled ds_read_b128)
    f32x4 sacc[4];
    #pragma unroll
    for (int ct = 0; ct < 4; ++ct)
      #pragma unroll
      for (int r = 0; r < 4; ++r) sacc[ct][r] = 0.f;
    __builtin_amdgcn_s_setprio(1);
    #pragma unroll
    for (int ct = 0; ct < 4; ++ct) {
      int row = ct * 16 + l15;
      f16x8 k0 = *(const f16x8*)&Kl[buf][row * 64 + ((g) ^ (row & 7)) * 8];
      f16x8 k1 = *(const f16x8*)&Kl[buf][row * 64 + ((4 + g) ^ (row & 7)) * 8];
      sacc[ct] = MFMAH(qf[0], k0, sacc[ct]);
      sacc[ct] = MFMAH(qf[1], k1, sacc[ct]);
    }
    __builtin_amdgcn_s_setprio(0);
    // hT-operand ks=0 loads (independent of P) issued before exp
    size_t vbase = ((size_t)(w * 128 + l15)) * (BB * TT) + b * TT + ob + g * 8;
    short8v vf0[8];
    #pragma unroll
    for (int dv = 0; dv < 8; ++dv)
      vf0[dv] = *(const short8v*)(hT + vbase + (size_t)dv * 16 * (BB * TT));
    // exp + mask + row-sum + P->LDS (bf16, XOR-swizzled)
    float psum[4] = {0.f, 0.f, 0.f, 0.f};
    #pragma unroll
    for (int ct = 0; ct < 4; ++ct) {
      #pragma unroll
      for (int r = 0; r < 4; ++r) {
        float s = sacc[ct][r];
        float p = __expf(fminf(s, 50.f));
        if (diag && (ct * 16 + l15 > w * 16 + g * 4 + r)) p = 0.f;
        psum[r] += p;
        int q = w * 16 + g * 4 + r;
        int byte = (q * 128 + (ct * 16 + l15) * 2) ^ ((q & 7) << 4);
        *(u16*)((char*)Pl[buf] + byte) = bf16_bits(p);
      }
    }
    #pragma unroll
    for (int r = 0; r < 4; ++r) {
      float v = psum[r];
      v += __shfl_xor(v, 1, 16);
      v += __shfl_xor(v, 2, 16);
      v += __shfl_xor(v, 4, 16);
      v += __shfl_xor(v, 8, 16);
      if (l15 == 0) rs_lds[w * 16 + g * 4 + r] += v;
    }
    // Only the 2 oldest VM ops (K-stage) must complete before the barrier;
    // the 8 vf0 loads stay in flight (register deps wait for them in PV).
    WAITVM(8);
    WAITLGKM();     // P ds_writes visible to other waves
    BAR();
    // PV: issue ks=1 hT loads first, then compute ks=0 with vf0
    short8v vf1[8];
    #pragma unroll
    for (int dv = 0; dv < 8; ++dv)
      vf1[dv] = *(const short8v*)(hT + vbase + 32 + (size_t)dv * 16 * (BB * TT));
    short8v pf[4];
    #pragma unroll
    for (int qt = 0; qt < 4; ++qt) {
      int q = qt * 16 + l15;
      int byte = (q * 128 + g * 16) ^ ((q & 7) << 4);
      pf[qt] = *(short8v*)((char*)Pl[buf] + byte);
    }
    __builtin_amdgcn_s_setprio(1);
    #pragma unroll
    for (int dv = 0; dv < 8; ++dv)
      #pragma unroll
      for (int qt = 0; qt < 4; ++qt)
        oacc[qt][dv] = MFMA16(pf[qt], vf0[dv], oacc[qt][dv]);
    __builtin_amdgcn_s_setprio(0);
    #pragma unroll
    for (int qt = 0; qt < 4; ++qt) {
      int q = qt * 16 + l15;
      int byte = (q * 128 + 64 + g * 16) ^ ((q & 7) << 4);
      pf[qt] = *(short8v*)((char*)Pl[buf] + byte);
    }
    __builtin_amdgcn_s_setprio(1);
    #pragma unroll
    for (int dv = 0; dv < 8; ++dv)
      #pragma unroll
      for (int qt = 0; qt < 4; ++qt)
        oacc[qt][dv] = MFMA16(pf[qt], vf1[dv], oacc[qt][dv]);
    __builtin_amdgcn_s_setprio(0);
  }
  // epilogue: normalize, write O' bf16 [bt][h*512+dm]
  __syncthreads();
  int hh2 = bh & 7;
  #pragma unroll
  for (int qt = 0; qt < 4; ++qt) {
    #pragma unroll
    for (int r = 0; r < 4; ++r) {
      int q = qt * 16 + g * 4 + r;
      float rs = 1.0f / (rs_lds[q] + 1e-10f);
      size_t rowbase = ((size_t)(b * TT + tt * 64 + q)) * (NH * DM) + hh2 * DM + w * 128 + l15;
      #pragma unroll
      for (int dv = 0; dv < 8; ++dv)
        o[rowbase + dv * 16] = bf16_bits(oacc[qt][dv][r] * rs);
    }
  }
}

extern "C" void kernel_launch(void* const* d_in, const int* in_sizes, int n_in,
                              void* d_out, int out_size, void* d_ws, size_t ws_size,
                              hipStream_t stream) {
  (void)in_sizes; (void)n_in; (void)out_size; (void)ws_size;
  const int*   x   = (const int*)d_in[0];
  const float* emb = (const float*)d_in[3];
  const float* pos = (const float*)d_in[4];
  const float* wq  = (const float*)d_in[5];
  const float* wk  = (const float*)d_in[6];
  const float* wv  = (const float*)d_in[7];
  const float* m0  = (const float*)d_in[8];
  const float* mb  = (const float*)d_in[9];
  const float* m1  = (const float*)d_in[10];
  const float* ue  = (const float*)d_in[11];
  const float* ub  = (const float*)d_in[12];
  float* out = (float*)d_out;
  float* ws  = (float*)d_ws;

  const int M = BB * TT;

  // ws layout: h f32 | hh bf16 | hf16 f16 | yb f32 | ueT bf16
  float*    h    = ws;
  u16*      hh   = (u16*)(ws + 4194304);
  _Float16* hf16 = (_Float16*)(ws + 6291456);
  float*    yb   = ws + 8388608;
  u16*      ueT  = (u16*)(ws + 12582912);

  // d_out scratch layout (u16 units):
  // hT [0,4.2M) | hid [4.2M,21.0M) | vsum [21.0M,25.2M) | qf16 [33.5M,+4.2M)
  // | kf16 [37.7M,+4.2M) | wT [41.9M,...) | Ob [67.1M,+33.5M)
  u16* outus = (u16*)d_out;
  u16* hT   = outus;
  u16* hid  = outus + 4194304;
  u16* vsum = outus + 20971520;
  _Float16* qf16 = (_Float16*)(outus + 33554432);
  u16* wT = outus + 41943040;
  _Float16* wqkT = (_Float16*)wT;                // 524288 f16 (q rows then k rows)
  u16* wvT2 = wT + 524288;                       // 2097152 (dv x 4096)
  u16* w0T  = wT + 2621440;                      // 1048576
  u16* w1T  = wT + 3670016;                      // 1048576
  u16* Ob   = outus + 67108864;                  // bf16 [bt][h*512+dm]

  embed_ln_kernel<<<M, 256, 0, stream>>>(x, emb, pos, h, hh, hf16);
  transpose_hT<<<dim3(128, 8), 256, 0, stream>>>(h, hT);

  for (int l = 0; l < NL; ++l) {
    transpose_layer<<<1152, 256, 0, stream>>>(
        wq + (size_t)l * NH * DM * DK, wk + (size_t)l * NH * DM * DK,
        wv + (size_t)l * NH * DM * DM, m0 + (size_t)l * DM * DH,
        m1 + (size_t)l * DH * DM,
        wqkT, wvT2, w0T, w1T);
    gemm_qk_f16<<<dim3(64, 8), 256, 0, stream>>>(hf16, wqkT, qf16, DM);
    attn_mfma_kernel<<<BB * NH * (TT / 64), 256, 0, stream>>>(
        qf16, qf16 + 4194304, hT, Ob);
    gemm_n64<4><<<dim3(64, 8), 256, 0, stream>>>(Ob, wvT2, vsum, M, DM, NH * DM);
    ln_residual_kernel<true><<<M, 256, 0, stream>>>(h, vsum, hh, hf16);
    gemm_mfma<1><<<dim3(64, 16), 256, 0, stream>>>(hh, w0T, mb + (size_t)l * DH, hid, M, DH, DM);
    gemm_n64<2><<<dim3(64, 8), 256, 0, stream>>>(hid, w1T, yb, M, DM, DH);
    ln_residual_kernel<false><<<M, 256, 0, stream>>>(h, yb, hh, hf16);
    if (l + 1 < NL)
      transpose_hT<<<dim3(128, 8), 256, 0, stream>>>(h, hT);
  }
  transpose_ue<<<dim3(8, 128), 256, 0, stream>>>(ue, ueT);
  gemm_mfma<3><<<dim3(64, 64), 256, 0, stream>>>(hh, ueT, ub, out, M, ND, DM);
}